// Round 6
// baseline (140.910 us; speedup 1.0000x reference)
//
#include <hip/hip_runtime.h>
#include <hip/hip_bf16.h>

#define B_ 8
#define N_ 512
#define F_ 128
#define H_ 4
#define U_ 32
#define LEAKY_ALPHA 0.2f
#define PS 520   // pbf row stride in bf16 elems (de-conflicts b128 frag reads)

typedef __attribute__((ext_vector_type(8))) short short8;
typedef __attribute__((ext_vector_type(4))) float f32x4;

static __device__ __forceinline__ short f2bf_s(float x) {
    __hip_bfloat16 hv = __float2bfloat16(x);
    return *reinterpret_cast<short*>(&hv);
}
static __device__ __forceinline__ float bf2f_s(short v) {
    return __uint_as_float(((unsigned)(unsigned short)v) << 16);
}
// Pin a float4's components in VGPRs: makes them opaque so the compiler
// cannot rematerialize the feeding loads inside the hot loop (the R2/R4/R5
// disease: VGPR_Count 52-84 with per-iteration reloads from L2).
static __device__ __forceinline__ void pin4(float4& v) {
    asm volatile("" : "+v"(v.x), "+v"(v.y), "+v"(v.z), "+v"(v.w));
}

// ---------------------------------------------------------------------------
// Kernel 1: projections.
//   hsrc  = x@Wsrc (f32)                  [bh][n][u]
//   hsrcT = bf16(x@Wsrc) transposed       [bh*32+u][n]   (MFMA B-frag layout)
//   hdstN = -(x@Wdst) (f32)               [bh][n][u]
//   Drow[j] = sum_u a_u d_ju ; ascaled = 0.8*a
// score(i,j) ~ D_j + sum_u (0.8 a_u) max(s_iu, -d_ju)   (0.2*A_i dropped;
// softmax shift-invariant).
// ---------------------------------------------------------------------------
__global__ __launch_bounds__(256) void proj_kernel(
    const float* __restrict__ x, const float* __restrict__ Wsrc,
    const float* __restrict__ Wdst, const float* __restrict__ a,
    float* __restrict__ hsrc, float* __restrict__ hdstN,
    float* __restrict__ Drow, float* __restrict__ ascaled,
    short* __restrict__ hsrcT)
{
    __shared__ float4 xlds[8 * 32];
    const int t  = threadIdx.x;
    const int r0 = blockIdx.x * 8;

    const float4* xg = (const float4*)x + (size_t)r0 * 32;
    xlds[t] = xg[t];
    __syncthreads();

    const int u     = t & 31;
    const int h     = (t >> 5) & 3;
    const int which = t >> 7;
    const float* W  = (which ? Wdst : Wsrc) + h * (F_ * U_) + u;

    float acc[8];
#pragma unroll
    for (int r = 0; r < 8; ++r) acc[r] = 0.f;

#pragma unroll 2
    for (int fc = 0; fc < 32; ++fc) {
        const float w0 = W[(4 * fc + 0) * U_];
        const float w1 = W[(4 * fc + 1) * U_];
        const float w2 = W[(4 * fc + 2) * U_];
        const float w3 = W[(4 * fc + 3) * U_];
#pragma unroll
        for (int r = 0; r < 8; ++r) {
            const float4 xv = xlds[r * 32 + fc];
            float s = acc[r];
            s = fmaf(xv.x, w0, s);
            s = fmaf(xv.y, w1, s);
            s = fmaf(xv.z, w2, s);
            s = fmaf(xv.w, w3, s);
            acc[r] = s;
        }
    }

    const float av = a[h * U_ + u];
    if (which == 1 && blockIdx.x == 0)
        ascaled[h * U_ + u] = (1.f - LEAKY_ALPHA) * av;

    const int b  = r0 >> 9;
    const int n0 = r0 & (N_ - 1);

    if (which == 0) {
        short8 pk;
#pragma unroll
        for (int r = 0; r < 8; ++r) {
            const size_t base = ((size_t)((b * H_ + h) * N_ + n0 + r) << 5) + u;
            hsrc[base] = acc[r];
            pk[r] = f2bf_s(acc[r]);
        }
        *(short8*)&hsrcT[((size_t)((b * H_ + h) * U_) + u) * N_ + n0] = pk;
    } else {
#pragma unroll
        for (int r = 0; r < 8; ++r) {
            const size_t base = ((size_t)((b * H_ + h) * N_ + n0 + r) << 5) + u;
            hdstN[base] = -acc[r];
            float v = acc[r] * av;
            v += __shfl_xor(v, 1);
            v += __shfl_xor(v, 2);
            v += __shfl_xor(v, 4);
            v += __shfl_xor(v, 8);
            v += __shfl_xor(v, 16);
            if (u == 0) Drow[(b * H_ + h) * N_ + n0 + r] = v;
        }
    }
}

// ---------------------------------------------------------------------------
// Kernel 2: attention. Identical structure to R5; the ONLY change is pin4()
// on s0/s1/av so the values stay in VGPRs across the j-loop.
// Block = 256 thr = 4 waves; tile = 8 i; grid = 32 bh x 64 tiles.
// Phase A: wave w owns i = {2w, 2w+1}; lane = (jsub 0..31, uh 0..1).
// Phase C: out = p @ srcT via mfma_f32_16x16x32_bf16, B-frags direct from
// global hsrcT; cross-wave K-reduce via 4 KB LDS scratch.
// ---------------------------------------------------------------------------
__global__ __launch_bounds__(256, 4) void attn_kernel(
    const float* __restrict__ hsrc, const float* __restrict__ hdstN,
    const float* __restrict__ Drow, const float* __restrict__ ascaled,
    const short* __restrict__ hsrcT, float* __restrict__ out)
{
    __shared__ __align__(16) short pbf[16 * PS];  // 16.6 KB p bf16 [i][j]
    __shared__ f32x4 scr[4][64];                  // 4 KB K-partials
    __shared__ float lfin[8];                     // 1/l per i

    const int t  = threadIdx.x;
    const int L  = t & 63;
    const int w  = __builtin_amdgcn_readfirstlane(t >> 6);
    const int tile = blockIdx.x & 63;
    const int bh   = blockIdx.x >> 6;
    const int h    = bh & 3;
    const int b    = bh >> 2;
    const size_t bhN = (size_t)bh * N_;
    const int ig0  = tile * 8;

    const int jsub = L & 31;
    const int uh   = L >> 5;

    // ---- Phase A setup: s rows (f32) + 0.8*a into registers, PINNED ----
    float4 s0[4], s1[4], av[4];
    {
        const float4* p0 = (const float4*)(hsrc + ((bhN + ig0 + 2 * w) << 5) + uh * 16);
        const float4* p1 = (const float4*)(hsrc + ((bhN + ig0 + 2 * w + 1) << 5) + uh * 16);
        const float4* pa = (const float4*)(ascaled + h * U_ + uh * 16);
#pragma unroll
        for (int q = 0; q < 4; ++q) { s0[q] = p0[q]; s1[q] = p1[q]; av[q] = pa[q]; }
#pragma unroll
        for (int q = 0; q < 4; ++q) { pin4(s0[q]); pin4(s1[q]); pin4(av[q]); }
    }

    const float* dp = hdstN + (bhN << 5) + jsub * 32 + uh * 16;
    const float* Dp = Drow + bhN + jsub;
    short* pw = pbf + (2 * w + uh) * PS + jsub;

    float l = 0.f;

#define GAT_STEP(dv, q)                                          \
    r0a = fmaf(av[q].x, fmaxf(s0[q].x, dv.x), r0a);              \
    r1a = fmaf(av[q].x, fmaxf(s1[q].x, dv.x), r1a);              \
    r0a = fmaf(av[q].y, fmaxf(s0[q].y, dv.y), r0a);              \
    r1a = fmaf(av[q].y, fmaxf(s1[q].y, dv.y), r1a);              \
    r0b = fmaf(av[q].z, fmaxf(s0[q].z, dv.z), r0b);              \
    r1b = fmaf(av[q].z, fmaxf(s1[q].z, dv.z), r1b);              \
    r0b = fmaf(av[q].w, fmaxf(s0[q].w, dv.w), r0b);              \
    r1b = fmaf(av[q].w, fmaxf(s1[q].w, dv.w), r1b);

#pragma unroll 2
    for (int it = 0; it < 16; ++it) {
        const float4 d0 = ((const float4*)dp)[0];
        const float4 d1 = ((const float4*)dp)[1];
        const float4 d2 = ((const float4*)dp)[2];
        const float4 d3 = ((const float4*)dp)[3];
        const float Dj = *Dp;
        float r0a = 0.f, r0b = 0.f, r1a = 0.f, r1b = 0.f;
        GAT_STEP(d0, 0)
        GAT_STEP(d1, 1)
        GAT_STEP(d2, 2)
        GAT_STEP(d3, 3)
        float r0 = r0a + r0b;
        float r1 = r1a + r1b;
        r0 += __shfl_xor(r0, 32);
        r1 += __shfl_xor(r1, 32);
        const float e = __expf(Dj + (uh ? r1 : r0));
        const short q = f2bf_s(e);
        pw[32 * it] = q;
        l += bf2f_s(q);
        dp += 1024;
        Dp += 32;
    }
#undef GAT_STEP

    // per-i l: i=2w+uh partials live on the 32 lanes with this uh
    l += __shfl_xor(l, 1);
    l += __shfl_xor(l, 2);
    l += __shfl_xor(l, 4);
    l += __shfl_xor(l, 8);
    l += __shfl_xor(l, 16);
    if (jsub == 0) lfin[2 * w + uh] = __builtin_amdgcn_rcpf(l);
    __syncthreads();

    // ---- Phase C: MFMA  out = p @ src ----
    const int m  = L & 15;
    const int kq = L >> 4;
    const int nt = w & 1;
    const int ks = w >> 1;
    const short* Ap = pbf + m * PS + ks * 256 + kq * 8;
    const short* Bp = hsrcT + ((size_t)bh * U_ + nt * 16 + m) * N_ + ks * 256 + kq * 8;

    f32x4 acc = {0.f, 0.f, 0.f, 0.f};
#pragma unroll
    for (int st = 0; st < 8; ++st) {
        const short8 af = *(const short8*)(Ap + st * 32);
        const short8 bf = *(const short8*)(Bp + st * 32);
        acc = __builtin_amdgcn_mfma_f32_16x16x32_bf16(af, bf, acc, 0, 0, 0);
    }
    scr[w][L] = acc;
    __syncthreads();

    if (w < 2 && kq < 2) {                    // wave w reduces ntile=w
        const f32x4 p0 = scr[w][L];
        const f32x4 p1 = scr[w + 2][L];
#pragma unroll
        for (int r = 0; r < 4; ++r) {
            const int il = kq * 4 + r;        // C/D: row=(lane>>4)*4+reg, <8 valid
            out[((size_t)(b * N_ + ig0 + il)) * (H_ * U_) + h * U_ + w * 16 + m]
                = (p0[r] + p1[r]) * lfin[il];
        }
    }
}

// ---------------------------------------------------------------------------
extern "C" void kernel_launch(void* const* d_in, const int* in_sizes, int n_in,
                              void* d_out, int out_size, void* d_ws, size_t ws_size,
                              hipStream_t stream) {
    const float* x    = (const float*)d_in[0];
    const float* Wsrc = (const float*)d_in[1];
    const float* Wdst = (const float*)d_in[2];
    const float* a    = (const float*)d_in[3];

    float* ws      = (float*)d_ws;
    float* hsrc    = ws;
    float* hdstN   = hsrc + (size_t)B_ * H_ * N_ * U_;
    float* Drow    = hdstN + (size_t)B_ * H_ * N_ * U_;
    float* ascaled = Drow + (size_t)B_ * H_ * N_;
    short* hsrcT   = (short*)(ascaled + H_ * U_);

    proj_kernel<<<(B_ * N_) / 8, 256, 0, stream>>>(x, Wsrc, Wdst, a,
                                                   hsrc, hdstN, Drow, ascaled,
                                                   hsrcT);
    attn_kernel<<<B_ * H_ * (N_ / 8), 256, 0, stream>>>(hsrc, hdstN, Drow,
                                                        ascaled, hsrcT,
                                                        (float*)d_out);
}

// Round 7
// 99.273 us; speedup vs baseline: 1.4194x; 1.4194x over previous
//
#include <hip/hip_runtime.h>
#include <hip/hip_bf16.h>

#define B_ 8
#define N_ 512
#define F_ 128
#define H_ 4
#define U_ 32
#define LEAKY_ALPHA 0.2f
#define PS 520     // pbf row stride (bf16 elems)
#define DS 36      // dlds row stride (floats): 16 subs -> 2 addrs/bank = free

typedef __attribute__((ext_vector_type(8))) short short8;
typedef __attribute__((ext_vector_type(4))) float f32x4;

static __device__ __forceinline__ short f2bf_s(float x) {
    __hip_bfloat16 hv = __float2bfloat16(x);
    return *reinterpret_cast<short*>(&hv);
}
static __device__ __forceinline__ float bf2f_s(short v) {
    return __uint_as_float(((unsigned)(unsigned short)v) << 16);
}

// ---------------------------------------------------------------------------
// Kernel 1: projections (unchanged from R5/R6).
//   hsrc  = x@Wsrc (f32)            [bh][n][u]
//   hsrcT = bf16(x@Wsrc)^T          [bh*32+u][n]  (MFMA B-frag layout)
//   hdstN = -(x@Wdst) (f32)         [bh][n][u]
//   Drow[j] = sum_u a_u d_ju ; ascaled = 0.8*a
// score(i,j) ~ D_j + sum_u (0.8 a_u) max(s_iu, -d_ju)  (0.2*A_i dropped;
// softmax shift-invariant).
// ---------------------------------------------------------------------------
__global__ __launch_bounds__(256) void proj_kernel(
    const float* __restrict__ x, const float* __restrict__ Wsrc,
    const float* __restrict__ Wdst, const float* __restrict__ a,
    float* __restrict__ hsrc, float* __restrict__ hdstN,
    float* __restrict__ Drow, float* __restrict__ ascaled,
    short* __restrict__ hsrcT)
{
    __shared__ float4 xlds[8 * 32];
    const int t  = threadIdx.x;
    const int r0 = blockIdx.x * 8;

    const float4* xg = (const float4*)x + (size_t)r0 * 32;
    xlds[t] = xg[t];
    __syncthreads();

    const int u     = t & 31;
    const int h     = (t >> 5) & 3;
    const int which = t >> 7;
    const float* W  = (which ? Wdst : Wsrc) + h * (F_ * U_) + u;

    float acc[8];
#pragma unroll
    for (int r = 0; r < 8; ++r) acc[r] = 0.f;

#pragma unroll 2
    for (int fc = 0; fc < 32; ++fc) {
        const float w0 = W[(4 * fc + 0) * U_];
        const float w1 = W[(4 * fc + 1) * U_];
        const float w2 = W[(4 * fc + 2) * U_];
        const float w3 = W[(4 * fc + 3) * U_];
#pragma unroll
        for (int r = 0; r < 8; ++r) {
            const float4 xv = xlds[r * 32 + fc];
            float s = acc[r];
            s = fmaf(xv.x, w0, s);
            s = fmaf(xv.y, w1, s);
            s = fmaf(xv.z, w2, s);
            s = fmaf(xv.w, w3, s);
            acc[r] = s;
        }
    }

    const float av = a[h * U_ + u];
    if (which == 1 && blockIdx.x == 0)
        ascaled[h * U_ + u] = (1.f - LEAKY_ALPHA) * av;

    const int b  = r0 >> 9;
    const int n0 = r0 & (N_ - 1);

    if (which == 0) {
        short8 pk;
#pragma unroll
        for (int r = 0; r < 8; ++r) {
            const size_t base = ((size_t)((b * H_ + h) * N_ + n0 + r) << 5) + u;
            hsrc[base] = acc[r];
            pk[r] = f2bf_s(acc[r]);
        }
        *(short8*)&hsrcT[((size_t)((b * H_ + h) * U_) + u) * N_ + n0] = pk;
    } else {
#pragma unroll
        for (int r = 0; r < 8; ++r) {
            const size_t base = ((size_t)((b * H_ + h) * N_ + n0 + r) << 5) + u;
            hdstN[base] = -acc[r];
            float v = acc[r] * av;
            v += __shfl_xor(v, 1);
            v += __shfl_xor(v, 2);
            v += __shfl_xor(v, 4);
            v += __shfl_xor(v, 8);
            v += __shfl_xor(v, 16);
            if (u == 0) Drow[(b * H_ + h) * N_ + n0 + r] = v;
        }
    }
}

// ---------------------------------------------------------------------------
// Kernel 2: attention. R1 skeleton (LDS-staged d, broadcast reads) + every
// validated improvement: max-trick scores, bf16 p, MFMA phase C, prefetch.
// Block = 256 thr = 4 waves; tile = 16 i; grid = 32 bh x 32 tiles.
// Thread = (i = t>>4, sub = t&15). d staged in 128-row LDS tiles (coalesced
// global float4 reads -> LDS, next tile prefetched into regs during compute).
// Phase A reads d via LDS broadcast (16 i-lanes share each address; stride
// 36 -> 2 addrs/bank = free). Scores -> exp -> bf16 p in LDS; l in regs.
// Phase C: out = p[16x512] @ src via mfma_f32_16x16x32_bf16, B-frags direct
// from global hsrcT (validated in R5: absmax = 1 bf16 ULP).
// ---------------------------------------------------------------------------
__global__ __launch_bounds__(256, 4) void attn_kernel(
    const float* __restrict__ hsrc, const float* __restrict__ hdstN,
    const float* __restrict__ Drow, const float* __restrict__ ascaled,
    const short* __restrict__ hsrcT, float* __restrict__ out)
{
    __shared__ float dlds[128 * DS];              // 18.0 KB d tile
    __shared__ __align__(16) short pbf[16 * PS];  // 16.6 KB p bf16 [i][j]
    __shared__ f32x4 scr[4][64];                  // 4 KB K-partials
    __shared__ float lfin[16];                    // 1/l per i

    const int t    = threadIdx.x;
    const int L    = t & 63;
    const int w    = __builtin_amdgcn_readfirstlane(t >> 6);
    const int tile = blockIdx.x & 31;
    const int bh   = blockIdx.x >> 5;
    const int h    = bh & 3;
    const int b    = bh >> 2;
    const size_t bhN = (size_t)bh * N_;
    const int ig0  = tile * 16;
    const int i    = t >> 4;
    const int sub  = t & 15;

    // s row (f32) + 0.8*a into registers
    float4 s4[8], a4[8];
    {
        const float4* sg = (const float4*)(hsrc + ((bhN + ig0 + i) << 5));
        const float4* ag = (const float4*)(ascaled + h * U_);
#pragma unroll
        for (int q = 0; q < 8; ++q) s4[q] = sg[q];
#pragma unroll
        for (int q = 0; q < 8; ++q) a4[q] = ag[q];
    }

    const float4* dg = (const float4*)(hdstN + (bhN << 5));  // 1024 f4/tile
    const float* Dr  = Drow + bhN;

    float l = 0.f;

    // prefetch tile 0
    float4 pre0 = dg[t];
    float4 pre1 = dg[t + 256];
    float4 pre2 = dg[t + 512];
    float4 pre3 = dg[t + 768];

    for (int jt = 0; jt < 4; ++jt) {
        __syncthreads();
        {   // commit prefetched tile to LDS
            const int i0 = t,       j0 = i0 >> 3, u0 = i0 & 7;
            const int i1 = t + 256, j1 = i1 >> 3, u1 = i1 & 7;
            const int i2 = t + 512, j2 = i2 >> 3, u2 = i2 & 7;
            const int i3 = t + 768, j3 = i3 >> 3, u3 = i3 & 7;
            *(float4*)&dlds[j0 * DS + u0 * 4] = pre0;
            *(float4*)&dlds[j1 * DS + u1 * 4] = pre1;
            *(float4*)&dlds[j2 * DS + u2 * 4] = pre2;
            *(float4*)&dlds[j3 * DS + u3 * 4] = pre3;
        }
        __syncthreads();
        if (jt < 3) {   // prefetch next tile (latency hidden by compute)
            const float4* dn = dg + (jt + 1) * 1024;
            pre0 = dn[t];
            pre1 = dn[t + 256];
            pre2 = dn[t + 512];
            pre3 = dn[t + 768];
        }

#pragma unroll
        for (int k = 0; k < 8; ++k) {
            const int jl = sub + 16 * k;
            const float4* dr = (const float4*)&dlds[jl * DS];
            float ra = 0.f, rb = 0.f;
#pragma unroll
            for (int q = 0; q < 8; q += 2) {
                const float4 d0 = dr[q];
                const float4 d1 = dr[q + 1];
                ra = fmaf(a4[q].x, fmaxf(s4[q].x, d0.x), ra);
                rb = fmaf(a4[q].y, fmaxf(s4[q].y, d0.y), rb);
                ra = fmaf(a4[q].z, fmaxf(s4[q].z, d0.z), ra);
                rb = fmaf(a4[q].w, fmaxf(s4[q].w, d0.w), rb);
                ra = fmaf(a4[q + 1].x, fmaxf(s4[q + 1].x, d1.x), ra);
                rb = fmaf(a4[q + 1].y, fmaxf(s4[q + 1].y, d1.y), rb);
                ra = fmaf(a4[q + 1].z, fmaxf(s4[q + 1].z, d1.z), ra);
                rb = fmaf(a4[q + 1].w, fmaxf(s4[q + 1].w, d1.w), rb);
            }
            const float Dj = Dr[jt * 128 + jl];
            const float e  = __expf(Dj + ra + rb);
            const short qv = f2bf_s(e);
            pbf[i * PS + jt * 128 + jl] = qv;
            l += bf2f_s(qv);
        }
    }

    // per-i l: partials live in the 16 sub-lanes (lane bits 0..3 = sub)
    l += __shfl_xor(l, 1);
    l += __shfl_xor(l, 2);
    l += __shfl_xor(l, 4);
    l += __shfl_xor(l, 8);
    if (sub == 0) lfin[i] = __builtin_amdgcn_rcpf(l);
    __syncthreads();

    // ---- Phase C: MFMA  out = p @ src ----
    const int m  = L & 15;
    const int kq = L >> 4;
    const int nt = w & 1;
    const int ks = w >> 1;
    const short* Ap = pbf + m * PS + ks * 256 + kq * 8;
    const short* Bp = hsrcT + ((size_t)bh * U_ + nt * 16 + m) * N_ + ks * 256 + kq * 8;

    f32x4 acc = {0.f, 0.f, 0.f, 0.f};
#pragma unroll
    for (int st = 0; st < 8; ++st) {
        const short8 af = *(const short8*)(Ap + st * 32);
        const short8 bf = *(const short8*)(Bp + st * 32);
        acc = __builtin_amdgcn_mfma_f32_16x16x32_bf16(af, bf, acc, 0, 0, 0);
    }
    scr[w][L] = acc;
    __syncthreads();

    if (w < 2) {                               // wave w reduces ntile=w
        const f32x4 p0 = scr[w][L];
        const f32x4 p1 = scr[w + 2][L];
#pragma unroll
        for (int r = 0; r < 4; ++r) {
            const int il = kq * 4 + r;         // C/D: row=(lane>>4)*4+reg
            out[((size_t)(b * N_ + ig0 + il)) * (H_ * U_) + h * U_ + w * 16 + m]
                = (p0[r] + p1[r]) * lfin[il];
        }
    }
}

// ---------------------------------------------------------------------------
extern "C" void kernel_launch(void* const* d_in, const int* in_sizes, int n_in,
                              void* d_out, int out_size, void* d_ws, size_t ws_size,
                              hipStream_t stream) {
    const float* x    = (const float*)d_in[0];
    const float* Wsrc = (const float*)d_in[1];
    const float* Wdst = (const float*)d_in[2];
    const float* a    = (const float*)d_in[3];

    float* ws      = (float*)d_ws;
    float* hsrc    = ws;
    float* hdstN   = hsrc + (size_t)B_ * H_ * N_ * U_;
    float* Drow    = hdstN + (size_t)B_ * H_ * N_ * U_;
    float* ascaled = Drow + (size_t)B_ * H_ * N_;
    short* hsrcT   = (short*)(ascaled + H_ * U_);

    proj_kernel<<<(B_ * N_) / 8, 256, 0, stream>>>(x, Wsrc, Wdst, a,
                                                   hsrc, hdstN, Drow, ascaled,
                                                   hsrcT);
    attn_kernel<<<B_ * H_ * (N_ / 16), 256, 0, stream>>>(hsrc, hdstN, Drow,
                                                         ascaled, hsrcT,
                                                         (float*)d_out);
}